// Round 5
// baseline (3203.503 us; speedup 1.0000x reference)
//
#include <hip/hip_runtime.h>

#define NN 30000
#define NE 480000
#define EPSV 0.3f

static __device__ __forceinline__ float nclean(float v) { return v != v ? 0.f : v; }

// ---------------------------------------------------------------------------
// GEMM: C[M,128] = A[M,KTOT] * B + bias(optional), M = NN rows.
// BT=true : B is [128,KTOT] row-major (C[v][j] = sum_k A[v][k]*B[j][k])
// BT=false: B is [KTOT,128] row-major (C[v][j] = sum_k A[v][k]*B[k][j])
// MODE 0: A[v][k] = nan-clean(A0[v*KTOT+k])                 (x input)
// MODE 1: A[v][k] = EPS*A0[v*KTOT+k] + A1[v*KTOT+k]         (residual + z)
// MODE 2: A = concat(A0[N,384], A1[N,128], A2[N,384], nan-clean A3[N,512])
// Epilogue: optional pre-activation store (stride 128) and/or relu store
//           (stride relu_stride, column offset relu_coloff).
// ---------------------------------------------------------------------------
template<int MODE, bool BT, int KTOT>
__global__ __launch_bounds__(256)
void gemm128(const float* __restrict__ A0, const float* __restrict__ A1,
             const float* __restrict__ A2, const float* __restrict__ A3,
             const float* __restrict__ B,  const float* __restrict__ bias,
             float* __restrict__ out_pre,  float* __restrict__ out_relu,
             int relu_stride, int relu_coloff)
{
    __shared__ float As[16][72];    // [k][row], padded
    __shared__ float Bs[16][132];   // [k][col], padded

    const int tid  = threadIdx.x;
    const int brow = blockIdx.x * 64;
    const int trow = tid >> 5;      // 0..7  -> rows trow*8 .. +7
    const int tcol = tid & 31;      // 0..31 -> cols tcol*4 .. +3

    float acc[8][4];
#pragma unroll
    for (int m = 0; m < 8; m++)
#pragma unroll
        for (int n = 0; n < 4; n++) acc[m][n] = 0.f;

    const int arow = tid >> 2;          // 0..63
    const int akq  = (tid & 3) << 2;    // 0,4,8,12
    const int grow = brow + arow;
    const bool rok = (grow < NN);

    for (int k0 = 0; k0 < KTOT; k0 += 16) {
        // ---- A tile (transpose into As[k][row]) ----
        float4 av = make_float4(0.f, 0.f, 0.f, 0.f);
        if (rok) {
            const int k = k0 + akq;
            if (MODE == 0) {
                av = *reinterpret_cast<const float4*>(A0 + (size_t)grow * KTOT + k);
                av.x = nclean(av.x); av.y = nclean(av.y);
                av.z = nclean(av.z); av.w = nclean(av.w);
            } else if (MODE == 1) {
                float4 h4 = *reinterpret_cast<const float4*>(A0 + (size_t)grow * KTOT + k);
                float4 z4 = *reinterpret_cast<const float4*>(A1 + (size_t)grow * KTOT + k);
                av.x = fmaf(EPSV, h4.x, z4.x); av.y = fmaf(EPSV, h4.y, z4.y);
                av.z = fmaf(EPSV, h4.z, z4.z); av.w = fmaf(EPSV, h4.w, z4.w);
            } else {
                if (k < 384) {
                    av = *reinterpret_cast<const float4*>(A0 + (size_t)grow * 384 + k);
                } else if (k < 512) {
                    av = *reinterpret_cast<const float4*>(A1 + (size_t)grow * 128 + (k - 384));
                } else if (k < 896) {
                    av = *reinterpret_cast<const float4*>(A2 + (size_t)grow * 384 + (k - 512));
                } else {
                    av = *reinterpret_cast<const float4*>(A3 + (size_t)grow * 512 + (k - 896));
                    av.x = nclean(av.x); av.y = nclean(av.y);
                    av.z = nclean(av.z); av.w = nclean(av.w);
                }
            }
        }
        As[akq + 0][arow] = av.x; As[akq + 1][arow] = av.y;
        As[akq + 2][arow] = av.z; As[akq + 3][arow] = av.w;

        // ---- B tile ----
        if (BT) {
#pragma unroll
            for (int r = 0; r < 2; r++) {
                const int idx = tid + r * 256;       // 0..511
                const int j   = idx >> 2;            // 0..127
                const int kq  = (idx & 3) << 2;
                float4 bv = *reinterpret_cast<const float4*>(B + (size_t)j * KTOT + k0 + kq);
                Bs[kq + 0][j] = bv.x; Bs[kq + 1][j] = bv.y;
                Bs[kq + 2][j] = bv.z; Bs[kq + 3][j] = bv.w;
            }
        } else {
#pragma unroll
            for (int r = 0; r < 2; r++) {
                const int idx = tid + r * 256;       // 0..511
                const int kk  = idx >> 5;            // 0..15
                const int cq  = (idx & 31) << 2;     // 0..124
                float4 bv = *reinterpret_cast<const float4*>(B + (size_t)(k0 + kk) * 128 + cq);
                *reinterpret_cast<float4*>(&Bs[kk][cq]) = bv;
            }
        }
        __syncthreads();

#pragma unroll
        for (int kk = 0; kk < 16; kk++) {
            float4 a0 = *reinterpret_cast<const float4*>(&As[kk][trow * 8]);
            float4 a1 = *reinterpret_cast<const float4*>(&As[kk][trow * 8 + 4]);
            float4 b  = *reinterpret_cast<const float4*>(&Bs[kk][tcol * 4]);
            const float am[8] = {a0.x, a0.y, a0.z, a0.w, a1.x, a1.y, a1.z, a1.w};
            const float bn[4] = {b.x, b.y, b.z, b.w};
#pragma unroll
            for (int m = 0; m < 8; m++)
#pragma unroll
                for (int n = 0; n < 4; n++)
                    acc[m][n] = fmaf(am[m], bn[n], acc[m][n]);
        }
        __syncthreads();
    }

    // ---- epilogue ----
#pragma unroll
    for (int m = 0; m < 8; m++) {
        const int row = brow + trow * 8 + m;
        if (row < NN) {
#pragma unroll
            for (int n = 0; n < 4; n++) {
                const int col = tcol * 4 + n;
                float v = acc[m][n];
                if (bias != nullptr) v += bias[col];
                if (out_pre  != nullptr) out_pre[(size_t)row * 128 + col] = v;
                if (out_relu != nullptr)
                    out_relu[(size_t)row * relu_stride + relu_coloff + col] = fmaxf(v, 0.f);
            }
        }
    }
}

// ---------------------------------------------------------------------------
// Per-node gate dots: hd[v] = h[v,:]·gw[0:D], hs[v] = h[v,:]·gw[D:2D]
// one wave per node
// ---------------------------------------------------------------------------
template<int D>
__global__ __launch_bounds__(256)
void gate_dots(const float* __restrict__ h, const float* __restrict__ gw,
               float* __restrict__ hd, float* __restrict__ hs)
{
    const int wv   = (blockIdx.x * 256 + threadIdx.x) >> 6;
    const int lane = threadIdx.x & 63;
    if (wv >= NN) return;
    const float* row = h + (size_t)wv * D;
    float sd = 0.f, ss = 0.f;
#pragma unroll
    for (int k = lane; k < D; k += 64) {
        const float hv = row[k];
        sd = fmaf(hv, gw[k], sd);
        ss = fmaf(hv, gw[D + k], ss);
    }
#pragma unroll
    for (int off = 32; off; off >>= 1) {
        sd += __shfl_xor(sd, off);
        ss += __shfl_xor(ss, off);
    }
    if (lane == 0) { hd[wv] = sd; hs[wv] = ss; }
}

// ---------------------------------------------------------------------------
// Edge scatter: z[dst] += d[dst]*d[src]*tanh(hd[dst]+hs[src]+gb) * h[src]
// one wave per edge, atomicAdd into z
// ---------------------------------------------------------------------------
template<int D>
__global__ __launch_bounds__(256)
void scatter_edges(const float* __restrict__ h,  const float* __restrict__ hd,
                   const float* __restrict__ hs, const float* __restrict__ dv,
                   const int* __restrict__ src,  const int* __restrict__ dst,
                   const float* __restrict__ gb, float* __restrict__ z)
{
    const int e    = (blockIdx.x * 256 + threadIdx.x) >> 6;
    const int lane = threadIdx.x & 63;
    if (e >= NE) return;
    const int s = src[e];
    const int t = dst[e];
    const float a = tanhf(hd[t] + hs[s] + gb[0]);
    const float w = dv[t] * dv[s] * a;
    const float* hrow = h + (size_t)s * D;
    float* zrow = z + (size_t)t * D;
#pragma unroll
    for (int f = lane; f < D; f += 64)
        atomicAdd(&zrow[f], w * hrow[f]);
}

// ---------------------------------------------------------------------------
// t3: out[v][c] = b3[c] + sum_j relu(scores[v][j]) * W3[c][j], c<16
// ---------------------------------------------------------------------------
__global__ __launch_bounds__(256)
void t3_kernel(const float* __restrict__ scores, const float* __restrict__ W3,
               const float* __restrict__ b3, float* __restrict__ out)
{
    const int idx = blockIdx.x * 256 + threadIdx.x;
    const int v = idx >> 4;
    const int c = idx & 15;
    if (v >= NN) return;
    const float4* s4 = reinterpret_cast<const float4*>(scores + (size_t)v * 128);
    const float4* w4 = reinterpret_cast<const float4*>(W3 + (size_t)c * 128);
    float acc = 0.f;
#pragma unroll
    for (int j = 0; j < 32; j++) {
        const float4 s = s4[j];
        const float4 w = w4[j];
        acc = fmaf(fmaxf(s.x, 0.f), w.x, acc);
        acc = fmaf(fmaxf(s.y, 0.f), w.y, acc);
        acc = fmaf(fmaxf(s.z, 0.f), w.z, acc);
        acc = fmaf(fmaxf(s.w, 0.f), w.w, acc);
    }
    out[idx] = acc + b3[c];
}

// ---------------------------------------------------------------------------
extern "C" void kernel_launch(void* const* d_in, const int* in_sizes, int n_in,
                              void* d_out, int out_size, void* d_ws, size_t ws_size,
                              hipStream_t stream)
{
    const float* x = (const float*)d_in[0];
    const int*   srcs[3] = {(const int*)d_in[1], (const int*)d_in[4], (const int*)d_in[7]};
    const int*   dsts[3] = {(const int*)d_in[2], (const int*)d_in[5], (const int*)d_in[8]};
    const float* dvs [3] = {(const float*)d_in[3], (const float*)d_in[6], (const float*)d_in[9]};
    const float* W_t1 = (const float*)d_in[10];
    const float* b_t1 = (const float*)d_in[11];
    const float *gW1[3], *gb1[3], *hw1[3], *gW2[3], *gb2[3], *hw2[3];
    for (int j = 0; j < 3; j++) {
        const int b = 12 + j * 6;
        gW1[j] = (const float*)d_in[b + 0];
        gb1[j] = (const float*)d_in[b + 1];
        hw1[j] = (const float*)d_in[b + 2];
        gW2[j] = (const float*)d_in[b + 3];
        gb2[j] = (const float*)d_in[b + 4];
        hw2[j] = (const float*)d_in[b + 5];
    }
    const float* W_t2 = (const float*)d_in[30];
    const float* b_t2 = (const float*)d_in[31];
    const float* W_t3 = (const float*)d_in[32];
    const float* b_t3 = (const float*)d_in[33];

    float* out  = (float*)d_out;                       // [NN,16]
    float* mid1 = out  + (size_t)NN * 16;              // [NN,128]
    float* mid2 = mid1 + (size_t)NN * 128;             // [NN,128]

    float* ws   = (float*)d_ws;
    float* raw1 = ws;                                  // NN*128
    float* raw2 = raw1 + (size_t)NN * 128;             // NN*384
    float* h2c  = raw2 + (size_t)NN * 384;             // NN*384
    float* z    = h2c  + (size_t)NN * 384;             // NN*384
    float* hd   = z    + (size_t)NN * 384;             // NN
    float* hs   = hd   + NN;                           // NN

    const dim3 blk(256);
    const int GG = (NN + 63) / 64;                     // 469 GEMM blocks
    const int WG = (NN * 64 + 255) / 256;              // one wave per node
    const int EG = (NE * 64 + 255) / 256;              // one wave per edge

    // t1: mid1 = x@W_t1.T + b ; raw1 = relu(mid1)
    gemm128<0, true, 512><<<GG, blk, 0, stream>>>(
        x, nullptr, nullptr, nullptr, W_t1, b_t1, mid1, raw1, 128, 0);

    // layer 1 (D=128): h1_j -> raw2 columns
    for (int j = 0; j < 3; j++) {
        gate_dots<128><<<WG, blk, 0, stream>>>(raw1, gW1[j], hd, hs);
        hipMemsetAsync(z, 0, (size_t)NN * 128 * sizeof(float), stream);
        scatter_edges<128><<<EG, blk, 0, stream>>>(
            raw1, hd, hs, dvs[j], srcs[j], dsts[j], gb1[j], z);
        gemm128<1, false, 128><<<GG, blk, 0, stream>>>(
            raw1, z, nullptr, nullptr, hw1[j], nullptr, nullptr, raw2, 384, j * 128);
    }

    // layer 2 (D=384): h2_j -> h2c columns
    for (int j = 0; j < 3; j++) {
        gate_dots<384><<<WG, blk, 0, stream>>>(raw2, gW2[j], hd, hs);
        hipMemsetAsync(z, 0, (size_t)NN * 384 * sizeof(float), stream);
        scatter_edges<384><<<EG, blk, 0, stream>>>(
            raw2, hd, hs, dvs[j], srcs[j], dsts[j], gb2[j], z);
        gemm128<1, false, 384><<<GG, blk, 0, stream>>>(
            raw2, z, nullptr, nullptr, hw2[j], nullptr, nullptr, h2c, 384, j * 128);
    }

    // t2: mid2 = concat(h2c, raw1, raw2, x) @ W_t2.T + b_t2
    gemm128<2, true, 1408><<<GG, blk, 0, stream>>>(
        h2c, raw1, raw2, x, W_t2, b_t2, mid2, nullptr, 0, 0);

    // t3: out = relu(mid2) @ W_t3.T + b_t3
    t3_kernel<<<(NN * 16 + 255) / 256, blk, 0, stream>>>(mid2, W_t3, b_t3, out);
}

// Round 8
// 1577.866 us; speedup vs baseline: 2.0303x; 2.0303x over previous
//
#include <hip/hip_runtime.h>

#define NN 30000
#define NE 480000
#define EPSV 0.3f

static __device__ __forceinline__ float nclean(float v) { return v != v ? 0.f : v; }

// ---------------------------------------------------------------------------
// GEMM: C[M,128] = A[M,KTOT] * B + bias(optional), M = NN rows.  (unchanged)
// ---------------------------------------------------------------------------
template<int MODE, bool BT, int KTOT>
__global__ __launch_bounds__(256)
void gemm128(const float* __restrict__ A0, const float* __restrict__ A1,
             const float* __restrict__ A2, const float* __restrict__ A3,
             const float* __restrict__ B,  const float* __restrict__ bias,
             float* __restrict__ out_pre,  float* __restrict__ out_relu,
             int relu_stride, int relu_coloff)
{
    __shared__ float As[16][72];    // [k][row], padded
    __shared__ float Bs[16][132];   // [k][col], padded

    const int tid  = threadIdx.x;
    const int brow = blockIdx.x * 64;
    const int trow = tid >> 5;      // 0..7  -> rows trow*8 .. +7
    const int tcol = tid & 31;      // 0..31 -> cols tcol*4 .. +3

    float acc[8][4];
#pragma unroll
    for (int m = 0; m < 8; m++)
#pragma unroll
        for (int n = 0; n < 4; n++) acc[m][n] = 0.f;

    const int arow = tid >> 2;          // 0..63
    const int akq  = (tid & 3) << 2;    // 0,4,8,12
    const int grow = brow + arow;
    const bool rok = (grow < NN);

    for (int k0 = 0; k0 < KTOT; k0 += 16) {
        float4 av = make_float4(0.f, 0.f, 0.f, 0.f);
        if (rok) {
            const int k = k0 + akq;
            if (MODE == 0) {
                av = *reinterpret_cast<const float4*>(A0 + (size_t)grow * KTOT + k);
                av.x = nclean(av.x); av.y = nclean(av.y);
                av.z = nclean(av.z); av.w = nclean(av.w);
            } else if (MODE == 1) {
                float4 h4 = *reinterpret_cast<const float4*>(A0 + (size_t)grow * KTOT + k);
                float4 z4 = *reinterpret_cast<const float4*>(A1 + (size_t)grow * KTOT + k);
                av.x = fmaf(EPSV, h4.x, z4.x); av.y = fmaf(EPSV, h4.y, z4.y);
                av.z = fmaf(EPSV, h4.z, z4.z); av.w = fmaf(EPSV, h4.w, z4.w);
            } else {
                if (k < 384) {
                    av = *reinterpret_cast<const float4*>(A0 + (size_t)grow * 384 + k);
                } else if (k < 512) {
                    av = *reinterpret_cast<const float4*>(A1 + (size_t)grow * 128 + (k - 384));
                } else if (k < 896) {
                    av = *reinterpret_cast<const float4*>(A2 + (size_t)grow * 384 + (k - 512));
                } else {
                    av = *reinterpret_cast<const float4*>(A3 + (size_t)grow * 512 + (k - 896));
                    av.x = nclean(av.x); av.y = nclean(av.y);
                    av.z = nclean(av.z); av.w = nclean(av.w);
                }
            }
        }
        As[akq + 0][arow] = av.x; As[akq + 1][arow] = av.y;
        As[akq + 2][arow] = av.z; As[akq + 3][arow] = av.w;

        if (BT) {
#pragma unroll
            for (int r = 0; r < 2; r++) {
                const int idx = tid + r * 256;
                const int j   = idx >> 2;
                const int kq  = (idx & 3) << 2;
                float4 bv = *reinterpret_cast<const float4*>(B + (size_t)j * KTOT + k0 + kq);
                Bs[kq + 0][j] = bv.x; Bs[kq + 1][j] = bv.y;
                Bs[kq + 2][j] = bv.z; Bs[kq + 3][j] = bv.w;
            }
        } else {
#pragma unroll
            for (int r = 0; r < 2; r++) {
                const int idx = tid + r * 256;
                const int kk  = idx >> 5;
                const int cq  = (idx & 31) << 2;
                float4 bv = *reinterpret_cast<const float4*>(B + (size_t)(k0 + kk) * 128 + cq);
                *reinterpret_cast<float4*>(&Bs[kk][cq]) = bv;
            }
        }
        __syncthreads();

#pragma unroll
        for (int kk = 0; kk < 16; kk++) {
            float4 a0 = *reinterpret_cast<const float4*>(&As[kk][trow * 8]);
            float4 a1 = *reinterpret_cast<const float4*>(&As[kk][trow * 8 + 4]);
            float4 b  = *reinterpret_cast<const float4*>(&Bs[kk][tcol * 4]);
            const float am[8] = {a0.x, a0.y, a0.z, a0.w, a1.x, a1.y, a1.z, a1.w};
            const float bn[4] = {b.x, b.y, b.z, b.w};
#pragma unroll
            for (int m = 0; m < 8; m++)
#pragma unroll
                for (int n = 0; n < 4; n++)
                    acc[m][n] = fmaf(am[m], bn[n], acc[m][n]);
        }
        __syncthreads();
    }

#pragma unroll
    for (int m = 0; m < 8; m++) {
        const int row = brow + trow * 8 + m;
        if (row < NN) {
#pragma unroll
            for (int n = 0; n < 4; n++) {
                const int col = tcol * 4 + n;
                float v = acc[m][n];
                if (bias != nullptr) v += bias[col];
                if (out_pre  != nullptr) out_pre[(size_t)row * 128 + col] = v;
                if (out_relu != nullptr)
                    out_relu[(size_t)row * relu_stride + relu_coloff + col] = fmaxf(v, 0.f);
            }
        }
    }
}

// ---------------------------------------------------------------------------
// Per-node gate dots: hd[v] = h[v,:]·gw[0:D], hs[v] = h[v,:]·gw[D:2D]
// ---------------------------------------------------------------------------
template<int D>
__global__ __launch_bounds__(256)
void gate_dots(const float* __restrict__ h, const float* __restrict__ gw,
               float* __restrict__ hd, float* __restrict__ hs)
{
    const int wv   = (blockIdx.x * 256 + threadIdx.x) >> 6;
    const int lane = threadIdx.x & 63;
    if (wv >= NN) return;
    const float* row = h + (size_t)wv * D;
    float sd = 0.f, ss = 0.f;
#pragma unroll
    for (int k = lane; k < D; k += 64) {
        const float hv = row[k];
        sd = fmaf(hv, gw[k], sd);
        ss = fmaf(hv, gw[D + k], ss);
    }
#pragma unroll
    for (int off = 32; off; off >>= 1) {
        sd += __shfl_xor(sd, off);
        ss += __shfl_xor(ss, off);
    }
    if (lane == 0) { hd[wv] = sd; hs[wv] = ss; }
}

// ---------------------------------------------------------------------------
// CSR build: histogram -> single-block scan -> fill (counting sort by dst)
// ---------------------------------------------------------------------------
__global__ __launch_bounds__(256)
void count_edges(const int* __restrict__ dst, int* __restrict__ cnt)
{
    const int i = blockIdx.x * 256 + threadIdx.x;
    if (i < NE) atomicAdd(&cnt[dst[i]], 1);
}

__global__ __launch_bounds__(1024)
void scan_rowptr(const int* __restrict__ cnt, int* __restrict__ row_ptr,
                 int* __restrict__ cursor)
{
    __shared__ int sdata[1024];
    __shared__ int s_carry;
    const int tid = threadIdx.x;
    if (tid == 0) s_carry = 0;
    __syncthreads();
    for (int base = 0; base < NN; base += 1024) {
        const int i = base + tid;
        const int v = (i < NN) ? cnt[i] : 0;
        sdata[tid] = v;
        __syncthreads();
#pragma unroll
        for (int off = 1; off < 1024; off <<= 1) {
            const int t = (tid >= off) ? sdata[tid - off] : 0;
            __syncthreads();
            sdata[tid] += t;
            __syncthreads();
        }
        const int excl = sdata[tid] - v + s_carry;
        if (i < NN) { row_ptr[i] = excl; cursor[i] = excl; }
        __syncthreads();
        if (tid == 1023) s_carry += sdata[1023];
        __syncthreads();
    }
    if (tid == 0) row_ptr[NN] = s_carry;   // == NE
}

__global__ __launch_bounds__(256)
void fill_csr(const int* __restrict__ src, const int* __restrict__ dst,
              int* __restrict__ cursor, int* __restrict__ perm_src)
{
    const int i = blockIdx.x * 256 + threadIdx.x;
    if (i < NE) {
        const int pos = atomicAdd(&cursor[dst[i]], 1);
        perm_src[pos] = src[i];
    }
}

// ---------------------------------------------------------------------------
// CSR gather, D=384: one wave per dst node.
// z[v] = sum_{e in CSR[v]} w_e * h[src_e],  w_e = d_v d_s tanh(hd_v+hs_s+gb)
// Weights computed 64-per-chunk in lanes, broadcast via __shfl.
// ---------------------------------------------------------------------------
__global__ __launch_bounds__(256)
void gather384(const float* __restrict__ h, const float* __restrict__ dv,
               const float* __restrict__ hd, const float* __restrict__ hs,
               const float* __restrict__ gb, const int* __restrict__ rp,
               const int* __restrict__ ps, float* __restrict__ z)
{
    const int lane = threadIdx.x & 63;
    const int v = (blockIdx.x * 256 + threadIdx.x) >> 6;   // 7500*4 == NN exactly
    const int start = rp[v], end = rp[v + 1];
    const float dvv = dv[v], hdv = hd[v], gb0 = gb[0];
    float4 a0 = {0.f, 0.f, 0.f, 0.f};
    float4 a1 = {0.f, 0.f, 0.f, 0.f};
    for (int chunk = start; chunk < end; chunk += 64) {
        const int nc = min(64, end - chunk);
        float wv_ = 0.f; int sv_ = 0;
        if (lane < nc) {
            const int s = ps[chunk + lane];
            sv_ = s;
            wv_ = dvv * dv[s] * tanhf(hdv + hs[s] + gb0);
        }
        for (int e = 0; e < nc; e++) {
            const float w = __shfl(wv_, e);
            const int   s = __shfl(sv_, e);
            const float4* hr = reinterpret_cast<const float4*>(h + (size_t)s * 384);
            const float4 b0 = hr[lane];
            a0.x = fmaf(w, b0.x, a0.x); a0.y = fmaf(w, b0.y, a0.y);
            a0.z = fmaf(w, b0.z, a0.z); a0.w = fmaf(w, b0.w, a0.w);
            if (lane < 32) {
                const float4 b1 = hr[64 + lane];
                a1.x = fmaf(w, b1.x, a1.x); a1.y = fmaf(w, b1.y, a1.y);
                a1.z = fmaf(w, b1.z, a1.z); a1.w = fmaf(w, b1.w, a1.w);
            }
        }
    }
    float4* zr = reinterpret_cast<float4*>(z + (size_t)v * 384);
    zr[lane] = a0;
    if (lane < 32) zr[64 + lane] = a1;
}

// ---------------------------------------------------------------------------
// CSR gather, D=128: one HALF-wave (32 lanes) per dst node, 2 nodes/wave.
// ---------------------------------------------------------------------------
__global__ __launch_bounds__(256)
void gather128(const float* __restrict__ h, const float* __restrict__ dv,
               const float* __restrict__ hd, const float* __restrict__ hs,
               const float* __restrict__ gb, const int* __restrict__ rp,
               const int* __restrict__ ps, float* __restrict__ z)
{
    const int lane = threadIdx.x & 63;
    const int half = lane >> 5;
    const int c    = lane & 31;
    const int v = (((blockIdx.x * 256 + threadIdx.x) >> 6) << 1) + half;  // 3750*8 == NN
    const int start = rp[v], end = rp[v + 1];
    const float dvv = dv[v], hdv = hd[v], gb0 = gb[0];
    const int base = half << 5;
    float4 a0 = {0.f, 0.f, 0.f, 0.f};
    for (int chunk = start; chunk < end; chunk += 32) {
        const int nc = min(32, end - chunk);
        float wv_ = 0.f; int sv_ = 0;
        if (c < nc) {
            const int s = ps[chunk + c];
            sv_ = s;
            wv_ = dvv * dv[s] * tanhf(hdv + hs[s] + gb0);
        }
        for (int e = 0; e < nc; e++) {
            const float w = __shfl(wv_, base | e);
            const int   s = __shfl(sv_, base | e);
            const float4 b = reinterpret_cast<const float4*>(h + (size_t)s * 128)[c];
            a0.x = fmaf(w, b.x, a0.x); a0.y = fmaf(w, b.y, a0.y);
            a0.z = fmaf(w, b.z, a0.z); a0.w = fmaf(w, b.w, a0.w);
        }
    }
    reinterpret_cast<float4*>(z + (size_t)v * 128)[c] = a0;
}

// ---------------------------------------------------------------------------
// t3: out[v][c] = b3[c] + sum_j relu(scores[v][j]) * W3[c][j], c<16
// ---------------------------------------------------------------------------
__global__ __launch_bounds__(256)
void t3_kernel(const float* __restrict__ scores, const float* __restrict__ W3,
               const float* __restrict__ b3, float* __restrict__ out)
{
    const int idx = blockIdx.x * 256 + threadIdx.x;
    const int v = idx >> 4;
    const int c = idx & 15;
    if (v >= NN) return;
    const float4* s4 = reinterpret_cast<const float4*>(scores + (size_t)v * 128);
    const float4* w4 = reinterpret_cast<const float4*>(W3 + (size_t)c * 128);
    float acc = 0.f;
#pragma unroll
    for (int j = 0; j < 32; j++) {
        const float4 s = s4[j];
        const float4 w = w4[j];
        acc = fmaf(fmaxf(s.x, 0.f), w.x, acc);
        acc = fmaf(fmaxf(s.y, 0.f), w.y, acc);
        acc = fmaf(fmaxf(s.z, 0.f), w.z, acc);
        acc = fmaf(fmaxf(s.w, 0.f), w.w, acc);
    }
    out[idx] = acc + b3[c];
}

// ---------------------------------------------------------------------------
extern "C" void kernel_launch(void* const* d_in, const int* in_sizes, int n_in,
                              void* d_out, int out_size, void* d_ws, size_t ws_size,
                              hipStream_t stream)
{
    const float* x = (const float*)d_in[0];
    const int*   srcs[3] = {(const int*)d_in[1], (const int*)d_in[4], (const int*)d_in[7]};
    const int*   dsts[3] = {(const int*)d_in[2], (const int*)d_in[5], (const int*)d_in[8]};
    const float* dvs [3] = {(const float*)d_in[3], (const float*)d_in[6], (const float*)d_in[9]};
    const float* W_t1 = (const float*)d_in[10];
    const float* b_t1 = (const float*)d_in[11];
    const float *gW1[3], *gb1[3], *hw1[3], *gW2[3], *gb2[3], *hw2[3];
    for (int j = 0; j < 3; j++) {
        const int b = 12 + j * 6;
        gW1[j] = (const float*)d_in[b + 0];
        gb1[j] = (const float*)d_in[b + 1];
        hw1[j] = (const float*)d_in[b + 2];
        gW2[j] = (const float*)d_in[b + 3];
        gb2[j] = (const float*)d_in[b + 4];
        hw2[j] = (const float*)d_in[b + 5];
    }
    const float* W_t2 = (const float*)d_in[30];
    const float* b_t2 = (const float*)d_in[31];
    const float* W_t3 = (const float*)d_in[32];
    const float* b_t3 = (const float*)d_in[33];

    float* out  = (float*)d_out;                       // [NN,16]
    float* mid1 = out  + (size_t)NN * 16;              // [NN,128]
    float* mid2 = mid1 + (size_t)NN * 128;             // [NN,128]

    // workspace layout (floats / ints, 4B each)
    float* ws   = (float*)d_ws;
    float* raw1 = ws;                                  // NN*128
    float* raw2 = raw1 + (size_t)NN * 128;             // NN*384
    float* h2c  = raw2 + (size_t)NN * 384;             // NN*384
    float* z    = h2c  + (size_t)NN * 384;             // NN*384
    float* hd   = z    + (size_t)NN * 384;             // NN
    float* hs   = hd   + NN;                           // NN
    int*   cnt    = (int*)(hs + NN);                   // NN
    int*   cursor = cnt + NN;                          // NN
    int*   rp[3];
    int*   psrc[3];
    int*   p = cursor + NN;
    for (int j = 0; j < 3; j++) { rp[j] = p; p += NN + 1; }
    for (int j = 0; j < 3; j++) { psrc[j] = p; p += NE; }

    const dim3 blk(256);
    const int GG = (NN + 63) / 64;                     // 469 GEMM blocks
    const int WG = (NN * 64 + 255) / 256;              // one wave per node
    const int CG = (NE + 255) / 256;                   // one thread per edge

    // ---- CSR build (once; reused by both layers) ----
    for (int j = 0; j < 3; j++) {
        hipMemsetAsync(cnt, 0, (size_t)NN * sizeof(int), stream);
        count_edges<<<CG, blk, 0, stream>>>(dsts[j], cnt);
        scan_rowptr<<<1, 1024, 0, stream>>>(cnt, rp[j], cursor);
        fill_csr<<<CG, blk, 0, stream>>>(srcs[j], dsts[j], cursor, psrc[j]);
    }

    // ---- t1: mid1 = x@W_t1.T + b ; raw1 = relu(mid1) ----
    gemm128<0, true, 512><<<GG, blk, 0, stream>>>(
        x, nullptr, nullptr, nullptr, W_t1, b_t1, mid1, raw1, 128, 0);

    // ---- layer 1 (D=128): h1_j -> raw2 columns ----
    for (int j = 0; j < 3; j++) {
        gate_dots<128><<<WG, blk, 0, stream>>>(raw1, gW1[j], hd, hs);
        gather128<<<NN / 8, blk, 0, stream>>>(raw1, dvs[j], hd, hs, gb1[j],
                                              rp[j], psrc[j], z);
        gemm128<1, false, 128><<<GG, blk, 0, stream>>>(
            raw1, z, nullptr, nullptr, hw1[j], nullptr, nullptr, raw2, 384, j * 128);
    }

    // ---- layer 2 (D=384): h2_j -> h2c columns ----
    for (int j = 0; j < 3; j++) {
        gate_dots<384><<<WG, blk, 0, stream>>>(raw2, gW2[j], hd, hs);
        gather384<<<NN / 4, blk, 0, stream>>>(raw2, dvs[j], hd, hs, gb2[j],
                                              rp[j], psrc[j], z);
        gemm128<1, false, 384><<<GG, blk, 0, stream>>>(
            raw2, z, nullptr, nullptr, hw2[j], nullptr, nullptr, h2c, 384, j * 128);
    }

    // ---- t2: mid2 = concat(h2c, raw1, raw2, x) @ W_t2.T + b_t2 ----
    gemm128<2, true, 1408><<<GG, blk, 0, stream>>>(
        h2c, raw1, raw2, x, W_t2, b_t2, mid2, nullptr, 0, 0);

    // ---- t3: out = relu(mid2) @ W_t3.T + b_t3 ----
    t3_kernel<<<(NN * 16 + 255) / 256, blk, 0, stream>>>(mid2, W_t3, b_t3, out);
}

// Round 13
// 980.928 us; speedup vs baseline: 3.2658x; 1.6085x over previous
//
#include <hip/hip_runtime.h>

#define NN 30000
#define NE 480000
#define EPSV 0.3f

typedef __attribute__((ext_vector_type(4))) float f32x4;
typedef __attribute__((ext_vector_type(8))) short s16x8;
typedef __attribute__((ext_vector_type(4))) short s16x4;

static __device__ __forceinline__ float nclean(float v) { return v != v ? 0.f : v; }
static __device__ __forceinline__ ushort f2bf(float f) {
    uint b = __float_as_uint(f);
    return (ushort)((b + 0x7FFFu + ((b >> 16) & 1u)) >> 16);   // RNE
}
static __device__ __forceinline__ float bf2f(ushort u) {
    return __uint_as_float(((uint)u) << 16);
}

// ---------------------------------------------------------------------------
// Weight prep: fp32 -> bf16, N-major [128][K]
// ---------------------------------------------------------------------------
__global__ __launch_bounds__(256)
void conv_nm(const float* __restrict__ in, ushort* __restrict__ out, int n)
{
    const int i = blockIdx.x * 256 + threadIdx.x;
    if (i < n) out[i] = f2bf(in[i]);
}

// hw [K][128] fp32 -> [128][K] bf16
__global__ __launch_bounds__(256)
void transpose_w(const float* __restrict__ in, ushort* __restrict__ out, int K)
{
    const int t = blockIdx.x * 256 + threadIdx.x;
    if (t >= K * 128) return;
    const int n = t & 127, k = t >> 7;
    out[(size_t)n * K + k] = f2bf(in[(size_t)k * 128 + n]);
}

// x [NN][512] fp32 (nan-clean) -> cat_bf slice col 896, stride 1408
__global__ __launch_bounds__(256)
void convert_x(const float* __restrict__ x, ushort* __restrict__ cat)
{
    const int t = blockIdx.x * 256 + threadIdx.x;        // NN*128 threads, 4 elems each
    const int v = t >> 7, c4 = (t & 127) * 4;
    const float4 f = *reinterpret_cast<const float4*>(x + (size_t)v * 512 + c4);
    ushort4 o;
    o.x = f2bf(nclean(f.x)); o.y = f2bf(nclean(f.y));
    o.z = f2bf(nclean(f.z)); o.w = f2bf(nclean(f.w));
    *reinterpret_cast<ushort4*>(cat + (size_t)v * 1408 + 896 + c4) = o;
}

// ---------------------------------------------------------------------------
// MFMA GEMM: C[M,128] = A_bf16[M,KTOT] * Bt_bf16[128][KTOT]^T (+bias)
// BM=32, BN=128, BK=64, 4 waves. Fragment k-layout: two half-K blocks
// (regs[0:1]: k=4g+j, regs[2:3]: k=16+4g+j), C/D: col=lane&15,row=g*4+i (m89).
// Epilogue: optional fp32 pre-act store (stride 128) + relu bf16 store.
// ---------------------------------------------------------------------------
static __device__ __forceinline__ s16x8 ldfrag(const ushort* p)
{
    s16x4 lo = *(const s16x4*)p;         // k-block 0..3
    s16x4 hi = *(const s16x4*)(p + 16);  // k-block 16..19
    s16x8 r;
    r[0] = lo[0]; r[1] = lo[1]; r[2] = lo[2]; r[3] = lo[3];
    r[4] = hi[0]; r[5] = hi[1]; r[6] = hi[2]; r[7] = hi[3];
    return r;
}

template<int KTOT, bool BIAS>
__global__ __launch_bounds__(256)
void gemm_mfma(const ushort* __restrict__ A, int lda, int acol,
               const ushort* __restrict__ Bt,
               const float* __restrict__ bias,
               float* __restrict__ outp,
               ushort* __restrict__ outb, int ldb_, int bcol)
{
    __shared__ ushort Asl[32][72];    // padded: 144 B rows -> conflict-free frags
    __shared__ ushort Bsl[128][72];

    const int tid  = threadIdx.x;
    const int wave = tid >> 6, lane = tid & 63;
    const int l15  = lane & 15, g = lane >> 4;
    const int brow = blockIdx.x * 32;

    f32x4 acc[2][2];
#pragma unroll
    for (int a_ = 0; a_ < 2; a_++)
#pragma unroll
        for (int b_ = 0; b_ < 2; b_++)
#pragma unroll
            for (int i = 0; i < 4; i++) acc[a_][b_][i] = 0.f;

    const int ar = tid >> 3, ac8 = (tid & 7) * 8;   // A stage: 32 rows x 64
    const int bn = tid >> 1, bc  = (tid & 1) * 32;  // B stage: 128 rows x 64

    for (int k0 = 0; k0 < KTOT; k0 += 64) {
        s16x8 av = {0, 0, 0, 0, 0, 0, 0, 0};
        if (brow + ar < NN)
            av = *(const s16x8*)(A + (size_t)(brow + ar) * lda + acol + k0 + ac8);
        *(s16x8*)&Asl[ar][ac8] = av;

        const ushort* bsrc = Bt + (size_t)bn * KTOT + k0 + bc;
#pragma unroll
        for (int c = 0; c < 4; c++)
            *(s16x8*)&Bsl[bn][bc + c * 8] = *(const s16x8*)(bsrc + c * 8);
        __syncthreads();

#pragma unroll
        for (int ks = 0; ks < 2; ks++) {
            s16x8 af[2], bfr[2];
#pragma unroll
            for (int rt = 0; rt < 2; rt++)
                af[rt] = ldfrag(&Asl[rt * 16 + l15][ks * 32 + 4 * g]);
#pragma unroll
            for (int ci = 0; ci < 2; ci++)
                bfr[ci] = ldfrag(&Bsl[(2 * wave + ci) * 16 + l15][ks * 32 + 4 * g]);
#pragma unroll
            for (int rt = 0; rt < 2; rt++)
#pragma unroll
                for (int ci = 0; ci < 2; ci++)
                    acc[rt][ci] = __builtin_amdgcn_mfma_f32_16x16x32_bf16(
                        af[rt], bfr[ci], acc[rt][ci], 0, 0, 0);
        }
        __syncthreads();
    }

#pragma unroll
    for (int rt = 0; rt < 2; rt++)
#pragma unroll
        for (int ci = 0; ci < 2; ci++) {
            const int col = (2 * wave + ci) * 16 + l15;
#pragma unroll
            for (int i = 0; i < 4; i++) {
                const int row = brow + rt * 16 + g * 4 + i;
                if (row < NN) {
                    float v = acc[rt][ci][i];
                    if (BIAS) v += bias[col];
                    if (outp) outp[(size_t)row * 128 + col] = v;
                    if (outb) outb[(size_t)row * ldb_ + bcol + col] = f2bf(fmaxf(v, 0.f));
                }
            }
        }
}

// ---------------------------------------------------------------------------
// Gate dots from bf16 rows (cat slice, stride 1408)
// ---------------------------------------------------------------------------
template<int D>
__global__ __launch_bounds__(256)
void gate_dots_bf(const ushort* __restrict__ hb, const float* __restrict__ gw,
                  float* __restrict__ hd, float* __restrict__ hs)
{
    const int wv   = (blockIdx.x * 256 + threadIdx.x) >> 6;
    const int lane = threadIdx.x & 63;
    if (wv >= NN) return;
    const uint* row = (const uint*)(hb + (size_t)wv * 1408);
    float sd = 0.f, ss = 0.f;
#pragma unroll
    for (int t = 0; t < D / 128; t++) {
        const int idx = t * 64 + lane;            // uint index: elems 2idx, 2idx+1
        const uint u = row[idx];
        const float h0 = bf2f((ushort)(u & 0xffff));
        const float h1 = bf2f((ushort)(u >> 16));
        sd = fmaf(h0, gw[2 * idx], fmaf(h1, gw[2 * idx + 1], sd));
        ss = fmaf(h0, gw[D + 2 * idx], fmaf(h1, gw[D + 2 * idx + 1], ss));
    }
#pragma unroll
    for (int off = 32; off; off >>= 1) {
        sd += __shfl_xor(sd, off);
        ss += __shfl_xor(ss, off);
    }
    if (lane == 0) { hd[wv] = sd; hs[wv] = ss; }
}

// ---------------------------------------------------------------------------
// CSR build (unchanged from round 8, verified)
// ---------------------------------------------------------------------------
__global__ __launch_bounds__(256)
void count_edges(const int* __restrict__ dst, int* __restrict__ cnt)
{
    const int i = blockIdx.x * 256 + threadIdx.x;
    if (i < NE) atomicAdd(&cnt[dst[i]], 1);
}

__global__ __launch_bounds__(1024)
void scan_rowptr(const int* __restrict__ cnt, int* __restrict__ row_ptr,
                 int* __restrict__ cursor)
{
    __shared__ int sdata[1024];
    __shared__ int s_carry;
    const int tid = threadIdx.x;
    if (tid == 0) s_carry = 0;
    __syncthreads();
    for (int base = 0; base < NN; base += 1024) {
        const int i = base + tid;
        const int v = (i < NN) ? cnt[i] : 0;
        sdata[tid] = v;
        __syncthreads();
#pragma unroll
        for (int off = 1; off < 1024; off <<= 1) {
            const int t = (tid >= off) ? sdata[tid - off] : 0;
            __syncthreads();
            sdata[tid] += t;
            __syncthreads();
        }
        const int excl = sdata[tid] - v + s_carry;
        if (i < NN) { row_ptr[i] = excl; cursor[i] = excl; }
        __syncthreads();
        if (tid == 1023) s_carry += sdata[1023];
        __syncthreads();
    }
    if (tid == 0) row_ptr[NN] = s_carry;
}

__global__ __launch_bounds__(256)
void fill_csr(const int* __restrict__ src, const int* __restrict__ dst,
              int* __restrict__ cursor, int* __restrict__ perm_src)
{
    const int i = blockIdx.x * 256 + threadIdx.x;
    if (i < NE) {
        const int pos = atomicAdd(&cursor[dst[i]], 1);
        perm_src[pos] = src[i];
    }
}

// ---------------------------------------------------------------------------
// CSR gather D=384 (bf16 rows from cat raw2-slice) + fused zres = eps*h + z
// ---------------------------------------------------------------------------
__global__ __launch_bounds__(256)
void gather384(const ushort* __restrict__ hb, const float* __restrict__ dv,
               const float* __restrict__ hd, const float* __restrict__ hs,
               const float* __restrict__ gb, const int* __restrict__ rp,
               const int* __restrict__ ps, ushort* __restrict__ zres)
{
    const int lane = threadIdx.x & 63;
    const int v = (blockIdx.x * 256 + threadIdx.x) >> 6;
    const int start = rp[v], end = rp[v + 1];
    const float dvv = dv[v], hdv = hd[v], gb0 = gb[0];
    float4 a0 = {0.f, 0.f, 0.f, 0.f};
    float4 a1 = {0.f, 0.f, 0.f, 0.f};
    for (int chunk = start; chunk < end; chunk += 64) {
        const int nc = min(64, end - chunk);
        float wv_ = 0.f; int sv_ = 0;
        if (lane < nc) {
            const int s = ps[chunk + lane];
            sv_ = s;
            wv_ = dvv * dv[s] * tanhf(hdv + hs[s] + gb0);
        }
        for (int e = 0; e < nc; e++) {
            const float w = __shfl(wv_, e);
            const int   s = __shfl(sv_, e);
            const ushort* hr = hb + (size_t)s * 1408;
            const ushort4 b0 = *(const ushort4*)(hr + 4 * lane);
            a0.x = fmaf(w, bf2f(b0.x), a0.x); a0.y = fmaf(w, bf2f(b0.y), a0.y);
            a0.z = fmaf(w, bf2f(b0.z), a0.z); a0.w = fmaf(w, bf2f(b0.w), a0.w);
            if (lane < 32) {
                const ushort4 b1 = *(const ushort4*)(hr + 256 + 4 * lane);
                a1.x = fmaf(w, bf2f(b1.x), a1.x); a1.y = fmaf(w, bf2f(b1.y), a1.y);
                a1.z = fmaf(w, bf2f(b1.z), a1.z); a1.w = fmaf(w, bf2f(b1.w), a1.w);
            }
        }
    }
    const ushort* hv = hb + (size_t)v * 1408;
    ushort* zr = zres + (size_t)v * 384;
    {
        const ushort4 h0 = *(const ushort4*)(hv + 4 * lane);
        ushort4 o;
        o.x = f2bf(fmaf(EPSV, bf2f(h0.x), a0.x));
        o.y = f2bf(fmaf(EPSV, bf2f(h0.y), a0.y));
        o.z = f2bf(fmaf(EPSV, bf2f(h0.z), a0.z));
        o.w = f2bf(fmaf(EPSV, bf2f(h0.w), a0.w));
        *(ushort4*)(zr + 4 * lane) = o;
    }
    if (lane < 32) {
        const ushort4 h1 = *(const ushort4*)(hv + 256 + 4 * lane);
        ushort4 o;
        o.x = f2bf(fmaf(EPSV, bf2f(h1.x), a1.x));
        o.y = f2bf(fmaf(EPSV, bf2f(h1.y), a1.y));
        o.z = f2bf(fmaf(EPSV, bf2f(h1.z), a1.z));
        o.w = f2bf(fmaf(EPSV, bf2f(h1.w), a1.w));
        *(ushort4*)(zr + 256 + 4 * lane) = o;
    }
}

// ---------------------------------------------------------------------------
// CSR gather D=128 (bf16 rows from cat raw1-slice), half-wave per node
// ---------------------------------------------------------------------------
__global__ __launch_bounds__(256)
void gather128(const ushort* __restrict__ hb, const float* __restrict__ dv,
               const float* __restrict__ hd, const float* __restrict__ hs,
               const float* __restrict__ gb, const int* __restrict__ rp,
               const int* __restrict__ ps, ushort* __restrict__ zres)
{
    const int lane = threadIdx.x & 63;
    const int half = lane >> 5;
    const int c    = lane & 31;
    const int v = (((blockIdx.x * 256 + threadIdx.x) >> 6) << 1) + half;
    const int start = rp[v], end = rp[v + 1];
    const float dvv = dv[v], hdv = hd[v], gb0 = gb[0];
    const int base = half << 5;
    float4 a0 = {0.f, 0.f, 0.f, 0.f};
    for (int chunk = start; chunk < end; chunk += 32) {
        const int nc = min(32, end - chunk);
        float wv_ = 0.f; int sv_ = 0;
        if (c < nc) {
            const int s = ps[chunk + c];
            sv_ = s;
            wv_ = dvv * dv[s] * tanhf(hdv + hs[s] + gb0);
        }
        for (int e = 0; e < nc; e++) {
            const float w = __shfl(wv_, base | e);
            const int   s = __shfl(sv_, base | e);
            const ushort4 b = *(const ushort4*)(hb + (size_t)s * 1408 + 4 * c);
            a0.x = fmaf(w, bf2f(b.x), a0.x); a0.y = fmaf(w, bf2f(b.y), a0.y);
            a0.z = fmaf(w, bf2f(b.z), a0.z); a0.w = fmaf(w, bf2f(b.w), a0.w);
        }
    }
    const ushort4 h0 = *(const ushort4*)(hb + (size_t)v * 1408 + 4 * c);
    ushort4 o;
    o.x = f2bf(fmaf(EPSV, bf2f(h0.x), a0.x));
    o.y = f2bf(fmaf(EPSV, bf2f(h0.y), a0.y));
    o.z = f2bf(fmaf(EPSV, bf2f(h0.z), a0.z));
    o.w = f2bf(fmaf(EPSV, bf2f(h0.w), a0.w));
    *(ushort4*)(zres + (size_t)v * 128 + 4 * c) = o;
}

// ---------------------------------------------------------------------------
// t3: out[v][c] = b3[c] + sum_j relu(mid2[v][j]) * W3[c][j]
// ---------------------------------------------------------------------------
__global__ __launch_bounds__(256)
void t3_kernel(const float* __restrict__ scores, const float* __restrict__ W3,
               const float* __restrict__ b3, float* __restrict__ out)
{
    const int idx = blockIdx.x * 256 + threadIdx.x;
    const int v = idx >> 4;
    const int c = idx & 15;
    if (v >= NN) return;
    const float4* s4 = reinterpret_cast<const float4*>(scores + (size_t)v * 128);
    const float4* w4 = reinterpret_cast<const float4*>(W3 + (size_t)c * 128);
    float acc = 0.f;
#pragma unroll
    for (int j = 0; j < 32; j++) {
        const float4 s = s4[j];
        const float4 w = w4[j];
        acc = fmaf(fmaxf(s.x, 0.f), w.x, acc);
        acc = fmaf(fmaxf(s.y, 0.f), w.y, acc);
        acc = fmaf(fmaxf(s.z, 0.f), w.z, acc);
        acc = fmaf(fmaxf(s.w, 0.f), w.w, acc);
    }
    out[idx] = acc + b3[c];
}

// ---------------------------------------------------------------------------
extern "C" void kernel_launch(void* const* d_in, const int* in_sizes, int n_in,
                              void* d_out, int out_size, void* d_ws, size_t ws_size,
                              hipStream_t stream)
{
    const float* x = (const float*)d_in[0];
    const int*   srcs[3] = {(const int*)d_in[1], (const int*)d_in[4], (const int*)d_in[7]};
    const int*   dsts[3] = {(const int*)d_in[2], (const int*)d_in[5], (const int*)d_in[8]};
    const float* dvs [3] = {(const float*)d_in[3], (const float*)d_in[6], (const float*)d_in[9]};
    const float* W_t1 = (const float*)d_in[10];
    const float* b_t1 = (const float*)d_in[11];
    const float *gW1[3], *gb1[3], *hw1[3], *gW2[3], *gb2[3], *hw2[3];
    for (int j = 0; j < 3; j++) {
        const int b = 12 + j * 6;
        gW1[j] = (const float*)d_in[b + 0];
        gb1[j] = (const float*)d_in[b + 1];
        hw1[j] = (const float*)d_in[b + 2];
        gW2[j] = (const float*)d_in[b + 3];
        gb2[j] = (const float*)d_in[b + 4];
        hw2[j] = (const float*)d_in[b + 5];
    }
    const float* W_t2 = (const float*)d_in[30];
    const float* b_t2 = (const float*)d_in[31];
    const float* W_t3 = (const float*)d_in[32];
    const float* b_t3 = (const float*)d_in[33];

    float* out  = (float*)d_out;                       // [NN,16]
    float* mid1 = out  + (size_t)NN * 16;              // [NN,128] fp32
    float* mid2 = mid1 + (size_t)NN * 128;             // [NN,128] fp32

    // ---- workspace layout (4B units) ----
    float*  ws    = (float*)d_ws;
    float*  hd    = ws;                                 // NN
    float*  hs    = hd + NN;                            // NN
    ushort* zres1 = (ushort*)(hs + NN);                 // NN*128 bf16
    ushort* zres2 = zres1 + (size_t)NN * 128;           // NN*384 bf16
    ushort* cat   = zres2 + (size_t)NN * 384;           // NN*1408 bf16: [h2c|raw1|raw2|x]
    ushort* wt1   = cat + (size_t)NN * 1408;            // 128*512
    ushort* wt2   = wt1 + 128 * 512;                    // 128*1408
    ushort* hw1t[3], *hw2t[3];
    {
        ushort* p = wt2 + 128 * 1408;
        for (int j = 0; j < 3; j++) { hw1t[j] = p; p += 128 * 128; }
        for (int j = 0; j < 3; j++) { hw2t[j] = p; p += 128 * 384; }
    }
    int* cnt    = (int*)(wt2 + 128 * 1408 + 3 * 128 * 128 + 3 * 128 * 384);
    int* cursor = cnt + NN;
    int* rp[3]; int* psrc[3];
    {
        int* p = cursor + NN;
        for (int j = 0; j < 3; j++) { rp[j] = p; p += NN + 1; }
        for (int j = 0; j < 3; j++) { psrc[j] = p; p += NE; }
    }

    const dim3 blk(256);
    const int GG = (NN + 31) / 32;                     // 938 MFMA-GEMM blocks
    const int WG = (NN * 64 + 255) / 256;              // one wave per node
    const int CG = (NE + 255) / 256;

    // ---- weight prep + x convert ----
    conv_nm<<<(128 * 512 + 255) / 256, blk, 0, stream>>>(W_t1, wt1, 128 * 512);
    conv_nm<<<(128 * 1408 + 255) / 256, blk, 0, stream>>>(W_t2, wt2, 128 * 1408);
    for (int j = 0; j < 3; j++) {
        transpose_w<<<(128 * 128 + 255) / 256, blk, 0, stream>>>(hw1[j], hw1t[j], 128);
        transpose_w<<<(128 * 384 + 255) / 256, blk, 0, stream>>>(hw2[j], hw2t[j], 384);
    }
    convert_x<<<NN * 128 / 256, blk, 0, stream>>>(x, cat);

    // ---- CSR build ----
    for (int j = 0; j < 3; j++) {
        hipMemsetAsync(cnt, 0, (size_t)NN * sizeof(int), stream);
        count_edges<<<CG, blk, 0, stream>>>(dsts[j], cnt);
        scan_rowptr<<<1, 1024, 0, stream>>>(cnt, rp[j], cursor);
        fill_csr<<<CG, blk, 0, stream>>>(srcs[j], dsts[j], cursor, psrc[j]);
    }

    // ---- t1: mid1 fp32 + relu-bf16 -> cat raw1 slice (col 384) ----
    gemm_mfma<512, true><<<GG, blk, 0, stream>>>(
        cat, 1408, 896, wt1, b_t1, mid1, cat, 1408, 384);

    // ---- layer 1 (D=128) ----
    for (int j = 0; j < 3; j++) {
        gate_dots_bf<128><<<WG, blk, 0, stream>>>(cat + 384, gW1[j], hd, hs);
        gather128<<<NN / 8, blk, 0, stream>>>(cat + 384, dvs[j], hd, hs, gb1[j],
                                              rp[j], psrc[j], zres1);
        gemm_mfma<128, false><<<GG, blk, 0, stream>>>(
            zres1, 128, 0, hw1t[j], nullptr, nullptr, cat, 1408, 512 + j * 128);
    }

    // ---- layer 2 (D=384) ----
    for (int j = 0; j < 3; j++) {
        gate_dots_bf<384><<<WG, blk, 0, stream>>>(cat + 512, gW2[j], hd, hs);
        gather384<<<NN / 4, blk, 0, stream>>>(cat + 512, dvs[j], hd, hs, gb2[j],
                                              rp[j], psrc[j], zres2);
        gemm_mfma<384, false><<<GG, blk, 0, stream>>>(
            zres2, 384, 0, hw2t[j], nullptr, nullptr, cat, 1408, j * 128);
    }

    // ---- t2: mid2 = cat @ W_t2^T + b_t2 (fp32 out) ----
    gemm_mfma<1408, true><<<GG, blk, 0, stream>>>(
        cat, 1408, 0, wt2, b_t2, mid2, nullptr, 0, 0);

    // ---- t3 ----
    t3_kernel<<<(NN * 16 + 255) / 256, blk, 0, stream>>>(mid2, W_t3, b_t3, out);
}

// Round 14
// 828.947 us; speedup vs baseline: 3.8645x; 1.1833x over previous
//
#include <hip/hip_runtime.h>

#define NN 30000
#define NE 480000
#define EPSV 0.3f
#define SCAN_B ((NN + 255) / 256)   // 118

typedef __attribute__((ext_vector_type(4))) float f32x4;
typedef __attribute__((ext_vector_type(8))) short s16x8;
typedef __attribute__((ext_vector_type(4))) short s16x4;

static __device__ __forceinline__ float nclean(float v) { return v != v ? 0.f : v; }
static __device__ __forceinline__ ushort f2bf(float f) {
    uint b = __float_as_uint(f);
    return (ushort)((b + 0x7FFFu + ((b >> 16) & 1u)) >> 16);   // RNE
}
static __device__ __forceinline__ float bf2f(ushort u) {
    return __uint_as_float(((uint)u) << 16);
}

// ---------------------------------------------------------------------------
// Weight prep: fp32 -> bf16, N-major [128][K]
// ---------------------------------------------------------------------------
__global__ __launch_bounds__(256)
void conv_nm(const float* __restrict__ in, ushort* __restrict__ out, int n)
{
    const int i = blockIdx.x * 256 + threadIdx.x;
    if (i < n) out[i] = f2bf(in[i]);
}

// hw [K][128] fp32 -> [128][K] bf16
__global__ __launch_bounds__(256)
void transpose_w(const float* __restrict__ in, ushort* __restrict__ out, int K)
{
    const int t = blockIdx.x * 256 + threadIdx.x;
    if (t >= K * 128) return;
    const int n = t & 127, k = t >> 7;
    out[(size_t)n * K + k] = f2bf(in[(size_t)k * 128 + n]);
}

// x [NN][512] fp32 (nan-clean) -> cat_bf slice col 896, stride 1408
__global__ __launch_bounds__(256)
void convert_x(const float* __restrict__ x, ushort* __restrict__ cat)
{
    const int t = blockIdx.x * 256 + threadIdx.x;        // NN*128 threads, 4 elems each
    const int v = t >> 7, c4 = (t & 127) * 4;
    const float4 f = *reinterpret_cast<const float4*>(x + (size_t)v * 512 + c4);
    ushort4 o;
    o.x = f2bf(nclean(f.x)); o.y = f2bf(nclean(f.y));
    o.z = f2bf(nclean(f.z)); o.w = f2bf(nclean(f.w));
    *reinterpret_cast<ushort4*>(cat + (size_t)v * 1408 + 896 + c4) = o;
}

// ---------------------------------------------------------------------------
// MFMA GEMM (unchanged from round 13, verified: absmax 0.039)
// ---------------------------------------------------------------------------
static __device__ __forceinline__ s16x8 ldfrag(const ushort* p)
{
    s16x4 lo = *(const s16x4*)p;         // k-block 0..3
    s16x4 hi = *(const s16x4*)(p + 16);  // k-block 16..19
    s16x8 r;
    r[0] = lo[0]; r[1] = lo[1]; r[2] = lo[2]; r[3] = lo[3];
    r[4] = hi[0]; r[5] = hi[1]; r[6] = hi[2]; r[7] = hi[3];
    return r;
}

template<int KTOT, bool BIAS>
__global__ __launch_bounds__(256)
void gemm_mfma(const ushort* __restrict__ A, int lda, int acol,
               const ushort* __restrict__ Bt,
               const float* __restrict__ bias,
               float* __restrict__ outp,
               ushort* __restrict__ outb, int ldb_, int bcol)
{
    __shared__ ushort Asl[32][72];
    __shared__ ushort Bsl[128][72];

    const int tid  = threadIdx.x;
    const int wave = tid >> 6, lane = tid & 63;
    const int l15  = lane & 15, g = lane >> 4;
    const int brow = blockIdx.x * 32;

    f32x4 acc[2][2];
#pragma unroll
    for (int a_ = 0; a_ < 2; a_++)
#pragma unroll
        for (int b_ = 0; b_ < 2; b_++)
#pragma unroll
            for (int i = 0; i < 4; i++) acc[a_][b_][i] = 0.f;

    const int ar = tid >> 3, ac8 = (tid & 7) * 8;
    const int bn = tid >> 1, bc  = (tid & 1) * 32;

    for (int k0 = 0; k0 < KTOT; k0 += 64) {
        s16x8 av = {0, 0, 0, 0, 0, 0, 0, 0};
        if (brow + ar < NN)
            av = *(const s16x8*)(A + (size_t)(brow + ar) * lda + acol + k0 + ac8);
        *(s16x8*)&Asl[ar][ac8] = av;

        const ushort* bsrc = Bt + (size_t)bn * KTOT + k0 + bc;
#pragma unroll
        for (int c = 0; c < 4; c++)
            *(s16x8*)&Bsl[bn][bc + c * 8] = *(const s16x8*)(bsrc + c * 8);
        __syncthreads();

#pragma unroll
        for (int ks = 0; ks < 2; ks++) {
            s16x8 af[2], bfr[2];
#pragma unroll
            for (int rt = 0; rt < 2; rt++)
                af[rt] = ldfrag(&Asl[rt * 16 + l15][ks * 32 + 4 * g]);
#pragma unroll
            for (int ci = 0; ci < 2; ci++)
                bfr[ci] = ldfrag(&Bsl[(2 * wave + ci) * 16 + l15][ks * 32 + 4 * g]);
#pragma unroll
            for (int rt = 0; rt < 2; rt++)
#pragma unroll
                for (int ci = 0; ci < 2; ci++)
                    acc[rt][ci] = __builtin_amdgcn_mfma_f32_16x16x32_bf16(
                        af[rt], bfr[ci], acc[rt][ci], 0, 0, 0);
        }
        __syncthreads();
    }

#pragma unroll
    for (int rt = 0; rt < 2; rt++)
#pragma unroll
        for (int ci = 0; ci < 2; ci++) {
            const int col = (2 * wave + ci) * 16 + l15;
#pragma unroll
            for (int i = 0; i < 4; i++) {
                const int row = brow + rt * 16 + g * 4 + i;
                if (row < NN) {
                    float v = acc[rt][ci][i];
                    if (BIAS) v += bias[col];
                    if (outp) outp[(size_t)row * 128 + col] = v;
                    if (outb) outb[(size_t)row * ldb_ + bcol + col] = f2bf(fmaxf(v, 0.f));
                }
            }
        }
}

// ---------------------------------------------------------------------------
// Gate dots from bf16 rows (cat slice, stride 1408)
// ---------------------------------------------------------------------------
template<int D>
__global__ __launch_bounds__(256)
void gate_dots_bf(const ushort* __restrict__ hb, const float* __restrict__ gw,
                  float* __restrict__ hd, float* __restrict__ hs)
{
    const int wv   = (blockIdx.x * 256 + threadIdx.x) >> 6;
    const int lane = threadIdx.x & 63;
    if (wv >= NN) return;
    const uint* row = (const uint*)(hb + (size_t)wv * 1408);
    float sd = 0.f, ss = 0.f;
#pragma unroll
    for (int t = 0; t < D / 128; t++) {
        const int idx = t * 64 + lane;
        const uint u = row[idx];
        const float h0 = bf2f((ushort)(u & 0xffff));
        const float h1 = bf2f((ushort)(u >> 16));
        sd = fmaf(h0, gw[2 * idx], fmaf(h1, gw[2 * idx + 1], sd));
        ss = fmaf(h0, gw[D + 2 * idx], fmaf(h1, gw[D + 2 * idx + 1], ss));
    }
#pragma unroll
    for (int off = 32; off; off >>= 1) {
        sd += __shfl_xor(sd, off);
        ss += __shfl_xor(ss, off);
    }
    if (lane == 0) { hd[wv] = sd; hs[wv] = ss; }
}

// ---------------------------------------------------------------------------
// CSR build: histogram -> hierarchical scan (118-block + top + finalize) -> fill
// ---------------------------------------------------------------------------
__global__ __launch_bounds__(256)
void count_edges(const int* __restrict__ dst, int* __restrict__ cnt)
{
    const int i = blockIdx.x * 256 + threadIdx.x;
    if (i < NE) atomicAdd(&cnt[dst[i]], 1);
}

__global__ __launch_bounds__(256)
void scan_part(const int* __restrict__ cnt, int* __restrict__ exc,
               int* __restrict__ bsum)
{
    __shared__ int sd[256];
    const int t = threadIdx.x;
    const int i = blockIdx.x * 256 + t;
    const int val = (i < NN) ? cnt[i] : 0;
    sd[t] = val;
    __syncthreads();
#pragma unroll
    for (int off = 1; off < 256; off <<= 1) {
        const int tmp = (t >= off) ? sd[t - off] : 0;
        __syncthreads();
        sd[t] += tmp;
        __syncthreads();
    }
    if (i < NN) exc[i] = sd[t] - val;
    if (t == 255) bsum[blockIdx.x] = sd[255];
}

__global__ __launch_bounds__(128)
void scan_top(int* __restrict__ bsum)     // in-place exclusive scan of SCAN_B sums
{
    __shared__ int sd[128];
    const int t = threadIdx.x;
    const int v = (t < SCAN_B) ? bsum[t] : 0;
    sd[t] = v;
    __syncthreads();
#pragma unroll
    for (int off = 1; off < 128; off <<= 1) {
        const int tmp = (t >= off) ? sd[t - off] : 0;
        __syncthreads();
        sd[t] += tmp;
        __syncthreads();
    }
    if (t < SCAN_B) bsum[t] = sd[t] - v;
}

__global__ __launch_bounds__(256)
void scan_fin(const int* __restrict__ exc, const int* __restrict__ bsum,
              int* __restrict__ rp, int* __restrict__ cursor)
{
    const int i = blockIdx.x * 256 + threadIdx.x;
    if (i < NN) {
        const int r = exc[i] + bsum[blockIdx.x];
        rp[i] = r; cursor[i] = r;
    }
    if (i == 0) rp[NN] = NE;   // total edges is static
}

__global__ __launch_bounds__(256)
void fill_csr(const int* __restrict__ src, const int* __restrict__ dst,
              int* __restrict__ cursor, int* __restrict__ perm_src)
{
    const int i = blockIdx.x * 256 + threadIdx.x;
    if (i < NE) {
        const int pos = atomicAdd(&cursor[dst[i]], 1);
        perm_src[pos] = src[i];
    }
}

// ---------------------------------------------------------------------------
// CSR gather D=384: one wave per dst. Lanes 0-47 load ushort8 (16B) covering
// the full 768B row; depth-2 prefetch (row e+1 in flight during e's FMAs).
// Fused epilogue: zres = bf16(eps*h + z). Accumulation order identical to r13.
// ---------------------------------------------------------------------------
__global__ __launch_bounds__(256)
void gather384(const ushort* __restrict__ hb, const float* __restrict__ dv,
               const float* __restrict__ hd, const float* __restrict__ hs,
               const float* __restrict__ gb, const int* __restrict__ rp,
               const int* __restrict__ ps, ushort* __restrict__ zres)
{
    const int lane = threadIdx.x & 63;
    const int v = (blockIdx.x * 256 + threadIdx.x) >> 6;   // 7500*4 == NN
    const int start = rp[v], end = rp[v + 1];
    const float dvv = dv[v], hdv = hd[v], gb0 = gb[0];
    const bool ld = (lane < 48);
    float a[8] = {0.f, 0.f, 0.f, 0.f, 0.f, 0.f, 0.f, 0.f};

    for (int chunk = start; chunk < end; chunk += 64) {
        const int nc = min(64, end - chunk);
        float wv_ = 0.f; int sv_ = 0;
        if (lane < nc) {
            const int s = ps[chunk + lane];
            sv_ = s;
            wv_ = dvv * dv[s] * tanhf(hdv + hs[s] + gb0);
        }
        const int s0 = __shfl(sv_, 0);
        s16x8 cur = {0, 0, 0, 0, 0, 0, 0, 0};
        if (ld) cur = *(const s16x8*)(hb + (size_t)s0 * 1408 + 8 * lane);
        for (int e = 0; e < nc; e++) {
            const float w = __shfl(wv_, e);
            s16x8 nxt = {0, 0, 0, 0, 0, 0, 0, 0};
            if (e + 1 < nc) {
                const int s1 = __shfl(sv_, e + 1);
                if (ld) nxt = *(const s16x8*)(hb + (size_t)s1 * 1408 + 8 * lane);
            }
#pragma unroll
            for (int i = 0; i < 8; i++)
                a[i] = fmaf(w, bf2f((ushort)cur[i]), a[i]);
            cur = nxt;
        }
    }
    if (ld) {
        const s16x8 h8 = *(const s16x8*)(hb + (size_t)v * 1408 + 8 * lane);
        s16x8 o;
#pragma unroll
        for (int i = 0; i < 8; i++)
            o[i] = (short)f2bf(fmaf(EPSV, bf2f((ushort)h8[i]), a[i]));
        *(s16x8*)(zres + (size_t)v * 384 + 8 * lane) = o;
    }
}

// ---------------------------------------------------------------------------
// CSR gather D=128: half-wave per dst; lanes 0-15 of each half load ushort8
// (16B, full 256B row); depth-2 prefetch; fused eps*h+z epilogue.
// ---------------------------------------------------------------------------
__global__ __launch_bounds__(256)
void gather128(const ushort* __restrict__ hb, const float* __restrict__ dv,
               const float* __restrict__ hd, const float* __restrict__ hs,
               const float* __restrict__ gb, const int* __restrict__ rp,
               const int* __restrict__ ps, ushort* __restrict__ zres)
{
    const int lane = threadIdx.x & 63;
    const int half = lane >> 5;
    const int c    = lane & 31;
    const int v = (((blockIdx.x * 256 + threadIdx.x) >> 6) << 1) + half;  // 3750*8 == NN
    const int start = rp[v], end = rp[v + 1];
    const float dvv = dv[v], hdv = hd[v], gb0 = gb[0];
    const int base = half << 5;
    const bool ld = (c < 16);
    float a[8] = {0.f, 0.f, 0.f, 0.f, 0.f, 0.f, 0.f, 0.f};

    for (int chunk = start; chunk < end; chunk += 32) {
        const int nc = min(32, end - chunk);
        float wv_ = 0.f; int sv_ = 0;
        if (c < nc) {
            const int s = ps[chunk + c];
            sv_ = s;
            wv_ = dvv * dv[s] * tanhf(hdv + hs[s] + gb0);
        }
        const int s0 = __shfl(sv_, base);
        s16x8 cur = {0, 0, 0, 0, 0, 0, 0, 0};
        if (ld) cur = *(const s16x8*)(hb + (size_t)s0 * 1408 + 8 * c);
        for (int e = 0; e < nc; e++) {
            const float w = __shfl(wv_, base | e);
            s16x8 nxt = {0, 0, 0, 0, 0, 0, 0, 0};
            if (e + 1 < nc) {
                const int s1 = __shfl(sv_, base | (e + 1));
                if (ld) nxt = *(const s16x8*)(hb + (size_t)s1 * 1408 + 8 * c);
            }
#pragma unroll
            for (int i = 0; i < 8; i++)
                a[i] = fmaf(w, bf2f((ushort)cur[i]), a[i]);
            cur = nxt;
        }
    }
    if (ld) {
        const s16x8 h8 = *(const s16x8*)(hb + (size_t)v * 1408 + 8 * c);
        s16x8 o;
#pragma unroll
        for (int i = 0; i < 8; i++)
            o[i] = (short)f2bf(fmaf(EPSV, bf2f((ushort)h8[i]), a[i]));
        *(s16x8*)(zres + (size_t)v * 128 + 8 * c) = o;
    }
}

// ---------------------------------------------------------------------------
// t3: out[v][c] = b3[c] + sum_j relu(mid2[v][j]) * W3[c][j]
// ---------------------------------------------------------------------------
__global__ __launch_bounds__(256)
void t3_kernel(const float* __restrict__ scores, const float* __restrict__ W3,
               const float* __restrict__ b3, float* __restrict__ out)
{
    const int idx = blockIdx.x * 256 + threadIdx.x;
    const int v = idx >> 4;
    const int c = idx & 15;
    if (v >= NN) return;
    const float4* s4 = reinterpret_cast<const float4*>(scores + (size_t)v * 128);
    const float4* w4 = reinterpret_cast<const float4*>(W3 + (size_t)c * 128);
    float acc = 0.f;
#pragma unroll
    for (int j = 0; j < 32; j++) {
        const float4 s = s4[j];
        const float4 w = w4[j];
        acc = fmaf(fmaxf(s.x, 0.f), w.x, acc);
        acc = fmaf(fmaxf(s.y, 0.f), w.y, acc);
        acc = fmaf(fmaxf(s.z, 0.f), w.z, acc);
        acc = fmaf(fmaxf(s.w, 0.f), w.w, acc);
    }
    out[idx] = acc + b3[c];
}

// ---------------------------------------------------------------------------
extern "C" void kernel_launch(void* const* d_in, const int* in_sizes, int n_in,
                              void* d_out, int out_size, void* d_ws, size_t ws_size,
                              hipStream_t stream)
{
    const float* x = (const float*)d_in[0];
    const int*   srcs[3] = {(const int*)d_in[1], (const int*)d_in[4], (const int*)d_in[7]};
    const int*   dsts[3] = {(const int*)d_in[2], (const int*)d_in[5], (const int*)d_in[8]};
    const float* dvs [3] = {(const float*)d_in[3], (const float*)d_in[6], (const float*)d_in[9]};
    const float* W_t1 = (const float*)d_in[10];
    const float* b_t1 = (const float*)d_in[11];
    const float *gW1[3], *gb1[3], *hw1[3], *gW2[3], *gb2[3], *hw2[3];
    for (int j = 0; j < 3; j++) {
        const int b = 12 + j * 6;
        gW1[j] = (const float*)d_in[b + 0];
        gb1[j] = (const float*)d_in[b + 1];
        hw1[j] = (const float*)d_in[b + 2];
        gW2[j] = (const float*)d_in[b + 3];
        gb2[j] = (const float*)d_in[b + 4];
        hw2[j] = (const float*)d_in[b + 5];
    }
    const float* W_t2 = (const float*)d_in[30];
    const float* b_t2 = (const float*)d_in[31];
    const float* W_t3 = (const float*)d_in[32];
    const float* b_t3 = (const float*)d_in[33];

    float* out  = (float*)d_out;                       // [NN,16]
    float* mid1 = out  + (size_t)NN * 16;              // [NN,128] fp32
    float* mid2 = mid1 + (size_t)NN * 128;             // [NN,128] fp32

    // ---- workspace layout (4B units) ----
    float*  ws    = (float*)d_ws;
    float*  hd    = ws;                                 // NN
    float*  hs    = hd + NN;                            // NN
    ushort* zres1 = (ushort*)(hs + NN);                 // NN*128 bf16
    ushort* zres2 = zres1 + (size_t)NN * 128;           // NN*384 bf16
    ushort* cat   = zres2 + (size_t)NN * 384;           // NN*1408 bf16: [h2c|raw1|raw2|x]
    ushort* wt1   = cat + (size_t)NN * 1408;            // 128*512
    ushort* wt2   = wt1 + 128 * 512;                    // 128*1408
    ushort* hw1t[3], *hw2t[3];
    {
        ushort* p = wt2 + 128 * 1408;
        for (int j = 0; j < 3; j++) { hw1t[j] = p; p += 128 * 128; }
        for (int j = 0; j < 3; j++) { hw2t[j] = p; p += 128 * 384; }
    }
    int* cnt    = (int*)(wt2 + 128 * 1408 + 3 * 128 * 128 + 3 * 128 * 384);
    int* cursor = cnt + NN;
    int* rp[3]; int* psrc[3];
    int* exc; int* bsum;
    {
        int* p = cursor + NN;
        for (int j = 0; j < 3; j++) { rp[j] = p; p += NN + 1; }
        for (int j = 0; j < 3; j++) { psrc[j] = p; p += NE; }
        exc  = p; p += NN;
        bsum = p; p += 128;
    }

    const dim3 blk(256);
    const int GG = (NN + 31) / 32;                     // 938 MFMA-GEMM blocks
    const int WG = (NN * 64 + 255) / 256;              // one wave per node
    const int CG = (NE + 255) / 256;

    // ---- weight prep + x convert ----
    conv_nm<<<(128 * 512 + 255) / 256, blk, 0, stream>>>(W_t1, wt1, 128 * 512);
    conv_nm<<<(128 * 1408 + 255) / 256, blk, 0, stream>>>(W_t2, wt2, 128 * 1408);
    for (int j = 0; j < 3; j++) {
        transpose_w<<<(128 * 128 + 255) / 256, blk, 0, stream>>>(hw1[j], hw1t[j], 128);
        transpose_w<<<(128 * 384 + 255) / 256, blk, 0, stream>>>(hw2[j], hw2t[j], 384);
    }
    convert_x<<<NN * 128 / 256, blk, 0, stream>>>(x, cat);

    // ---- CSR build (hierarchical scan) ----
    for (int j = 0; j < 3; j++) {
        hipMemsetAsync(cnt, 0, (size_t)NN * sizeof(int), stream);
        count_edges<<<CG, blk, 0, stream>>>(dsts[j], cnt);
        scan_part<<<SCAN_B, blk, 0, stream>>>(cnt, exc, bsum);
        scan_top<<<1, 128, 0, stream>>>(bsum);
        scan_fin<<<SCAN_B, blk, 0, stream>>>(exc, bsum, rp[j], cursor);
        fill_csr<<<CG, blk, 0, stream>>>(srcs[j], dsts[j], cursor, psrc[j]);
    }

    // ---- t1: mid1 fp32 + relu-bf16 -> cat raw1 slice (col 384) ----
    gemm_mfma<512, true><<<GG, blk, 0, stream>>>(
        cat, 1408, 896, wt1, b_t1, mid1, cat, 1408, 384);

    // ---- layer 1 (D=128) ----
    for (int j = 0; j < 3; j++) {
        gate_dots_bf<128><<<WG, blk, 0, stream>>>(cat + 384, gW1[j], hd, hs);
        gather128<<<NN / 8, blk, 0, stream>>>(cat + 384, dvs[j], hd, hs, gb1[j],
                                              rp[j], psrc[j], zres1);
        gemm_mfma<128, false><<<GG, blk, 0, stream>>>(
            zres1, 128, 0, hw1t[j], nullptr, nullptr, cat, 1408, 512 + j * 128);
    }

    // ---- layer 2 (D=384) ----
    for (int j = 0; j < 3; j++) {
        gate_dots_bf<384><<<WG, blk, 0, stream>>>(cat + 512, gW2[j], hd, hs);
        gather384<<<NN / 4, blk, 0, stream>>>(cat + 512, dvs[j], hd, hs, gb2[j],
                                              rp[j], psrc[j], zres2);
        gemm_mfma<384, false><<<GG, blk, 0, stream>>>(
            zres2, 384, 0, hw2t[j], nullptr, nullptr, cat, 1408, j * 128);
    }

    // ---- t2: mid2 = cat @ W_t2^T + b_t2 (fp32 out) ----
    gemm_mfma<1408, true><<<GG, blk, 0, stream>>>(
        cat, 1408, 0, wt2, b_t2, mid2, nullptr, 0, 0);

    // ---- t3 ----
    t3_kernel<<<(NN * 16 + 255) / 256, blk, 0, stream>>>(mid2, W_t3, b_t3, out);
}